// Round 1
// baseline (917.713 us; speedup 1.0000x reference)
//
#include <hip/hip_runtime.h>
#include <hip/hip_bf16.h>
#include <stdint.h>
#include <stddef.h>

#define NODES 100000
#define EDGES 1600000

typedef float f4 __attribute__((ext_vector_type(4)));
typedef unsigned short u16x8 __attribute__((ext_vector_type(8)));

__device__ __forceinline__ float bf2f(unsigned short u) {
  union { unsigned int i; float f; } v;
  v.i = ((unsigned int)u) << 16;
  return v.f;
}
__device__ __forceinline__ unsigned short f2bf(float f) {
  union { float f; unsigned int i; } v;
  v.f = f;
  unsigned int r = (v.i + 0x7FFFu + ((v.i >> 16) & 1u)) >> 16;  // RNE
  return (unsigned short)r;
}

// ---------------------------------------------------------------------------
// Kernel 1: per-node precompute  PQ[n][0:128] = z[n] @ W1[0:64,:]
//                                PQ[n][128:256] = z[n] @ W1[64:128,:]
// stored bf16. Block = 256 threads (one per output column), 16 nodes/block.
// z row reads are wave-uniform -> SMEM; weight column cached in 64 VGPRs.
// ---------------------------------------------------------------------------
__global__ __launch_bounds__(256) void node_pq_kernel(
    const float* __restrict__ z, const float* __restrict__ W1,
    unsigned short* __restrict__ PQ) {
  const int j = threadIdx.x;            // 0..255
  const int n0 = blockIdx.x * 16;
  const float* wbase = (j < 128) ? (W1 + j) : (W1 + 64 * 128 + (j - 128));
  float wcol[64];
#pragma unroll
  for (int k = 0; k < 64; ++k) wcol[k] = wbase[(size_t)k * 128];
#pragma unroll 1
  for (int n = 0; n < 16; ++n) {
    const float* zr = z + (size_t)(n0 + n) * 64;
    float a = 0.f;
#pragma unroll
    for (int k = 0; k < 64; ++k) a = fmaf(zr[k], wcol[k], a);
    PQ[(size_t)(n0 + n) * 256 + j] = f2bf(a);
  }
}

// ---------------------------------------------------------------------------
// Kernel 2: one lane = one edge.
//  h1[j] = relu(P[src][j] + Q[dst][j] + ea @ W1c[:,j] + b1[j])   (fp32)
//  acc[i] += h1[j] * W2[j][i]  (fused per 8-j chunk, acc[64] in VGPRs)
//  out = relu(acc+b2) @ W3 + b3
// All weight reads wave-uniform -> s_load; inner loop pure v_fmac.
// ---------------------------------------------------------------------------
template <bool PRECOMP>
__global__ __launch_bounds__(256) void edge_mlp_kernel(
    const float* __restrict__ z,
    const int* __restrict__ eidx,
    const float* __restrict__ eattr,
    const float* __restrict__ W1, const float* __restrict__ b1,
    const float* __restrict__ W2, const float* __restrict__ b2,
    const float* __restrict__ W3, const float* __restrict__ b3,
    const unsigned short* __restrict__ PQ,
    float* __restrict__ out) {
  const int e = blockIdx.x * 256 + threadIdx.x;
  const int src = eidx[e];
  const int dst = eidx[EDGES + e];

  float eav[8];
  {
    const f4* eap = (const f4*)(eattr + (size_t)e * 8);
    f4 ea0 = eap[0], ea1 = eap[1];
#pragma unroll
    for (int a = 0; a < 4; ++a) { eav[a] = ea0[a]; eav[4 + a] = ea1[a]; }
  }

  float acc[64];
#pragma unroll
  for (int i = 0; i < 64; ++i) acc[i] = 0.f;

  if constexpr (PRECOMP) {
    const u16x8* Pp = (const u16x8*)(PQ + (size_t)src * 256);
    const u16x8* Qp = (const u16x8*)(PQ + (size_t)dst * 256 + 128);
    u16x8 p8 = Pp[0], q8 = Qp[0];
#pragma unroll 1
    for (int jc = 0; jc < 16; ++jc) {
      u16x8 pn = p8, qn = q8;
      if (jc < 15) { pn = Pp[jc + 1]; qn = Qp[jc + 1]; }  // prefetch next chunk
      float h[8];
#pragma unroll
      for (int ii = 0; ii < 8; ++ii) {
        const int jj = jc * 8 + ii;
        float s = bf2f(p8[ii]) + bf2f(q8[ii]) + b1[jj];
#pragma unroll
        for (int a = 0; a < 8; ++a)
          s = fmaf(eav[a], W1[(size_t)(128 + a) * 128 + jj], s);
        h[ii] = fmaxf(s, 0.f);
      }
#pragma unroll
      for (int ii = 0; ii < 8; ++ii) {
        const float hv = h[ii];
        const float* w2r = W2 + (size_t)(jc * 8 + ii) * 64;
#pragma unroll
        for (int i = 0; i < 64; ++i) acc[i] = fmaf(hv, w2r[i], acc[i]);
      }
      p8 = pn; q8 = qn;
    }
  } else {
    // Fallback (ws too small): full layer-1 from z, correctness-first.
    float zsv[64], zdv[64];
    {
      const f4* zsp = (const f4*)(z + (size_t)src * 64);
      const f4* zdp = (const f4*)(z + (size_t)dst * 64);
#pragma unroll
      for (int q = 0; q < 16; ++q) {
        f4 a = zsp[q], b = zdp[q];
#pragma unroll
        for (int t = 0; t < 4; ++t) { zsv[q * 4 + t] = a[t]; zdv[q * 4 + t] = b[t]; }
      }
    }
#pragma unroll 1
    for (int jc = 0; jc < 16; ++jc) {
      float h[8];
#pragma unroll
      for (int ii = 0; ii < 8; ++ii) {
        const int jj = jc * 8 + ii;
        float s = b1[jj];
#pragma unroll
        for (int a = 0; a < 8; ++a)
          s = fmaf(eav[a], W1[(size_t)(128 + a) * 128 + jj], s);
        h[ii] = s;
      }
#pragma unroll
      for (int k = 0; k < 64; ++k) {
        const float* w1a = W1 + (size_t)k * 128 + jc * 8;
        const float* w1b = W1 + (size_t)(64 + k) * 128 + jc * 8;
#pragma unroll
        for (int ii = 0; ii < 8; ++ii)
          h[ii] = fmaf(zsv[k], w1a[ii], fmaf(zdv[k], w1b[ii], h[ii]));
      }
#pragma unroll
      for (int ii = 0; ii < 8; ++ii) {
        const float hv = fmaxf(h[ii], 0.f);
        const float* w2r = W2 + (size_t)(jc * 8 + ii) * 64;
#pragma unroll
        for (int i = 0; i < 64; ++i) acc[i] = fmaf(hv, w2r[i], acc[i]);
      }
    }
  }

  float res = b3[0];
#pragma unroll
  for (int i = 0; i < 64; ++i) {
    float h2 = fmaxf(acc[i] + b2[i], 0.f);
    res = fmaf(h2, W3[i], res);
  }
  out[e] = res;
}

extern "C" void kernel_launch(void* const* d_in, const int* in_sizes, int n_in,
                              void* d_out, int out_size, void* d_ws, size_t ws_size,
                              hipStream_t stream) {
  const float* z     = (const float*)d_in[0];
  const int*   eidx  = (const int*)d_in[1];
  const float* eattr = (const float*)d_in[2];
  const float* W1    = (const float*)d_in[3];
  const float* b1    = (const float*)d_in[4];
  const float* W2    = (const float*)d_in[5];
  const float* b2    = (const float*)d_in[6];
  const float* W3    = (const float*)d_in[7];
  const float* b3    = (const float*)d_in[8];
  float* out = (float*)d_out;

  const size_t pq_bytes = (size_t)NODES * 256 * sizeof(unsigned short);
  if (ws_size >= pq_bytes) {
    unsigned short* PQ = (unsigned short*)d_ws;
    node_pq_kernel<<<NODES / 16, 256, 0, stream>>>(z, W1, PQ);
    edge_mlp_kernel<true><<<EDGES / 256, 256, 0, stream>>>(
        z, eidx, eattr, W1, b1, W2, b2, W3, b3, PQ, out);
  } else {
    edge_mlp_kernel<false><<<EDGES / 256, 256, 0, stream>>>(
        z, eidx, eattr, W1, b1, W2, b2, W3, b3, nullptr, out);
  }
}